// Round 15
// baseline (269.665 us; speedup 1.0000x reference)
//
#include <hip/hip_runtime.h>

#define FIN 128
#define HID 64
#define CLS 32

#define BSH 7            // bucket covers 128 nodes
#define BNODES 128
#define GB 256           // chunks / blocks in sort pass (CHUNK=6250 @ E=1.6M)
#define BCAP 4096        // max records per bucket staged in LDS (mean ~2046)
#define SCAP 6272        // >= CHUNK: per-block staging capacity
#define NBUKP 800        // padded per-block loffB stride (>= NBUK+1)

using bfrag = __attribute__((ext_vector_type(8))) short;   // 8 bf16 (4 VGPRs)
using cfrag = __attribute__((ext_vector_type(4))) float;   // 4 fp32 acc

__device__ inline unsigned short f2bf(float x) {
  unsigned u = __float_as_uint(x);
  return (unsigned short)((u + 0x7FFFu + ((u >> 16) & 1u)) >> 16);
}
__device__ inline void bf8_to_f32(int4 v, float* f) {
  f[0] = __uint_as_float((unsigned)v.x << 16);
  f[1] = __uint_as_float((unsigned)v.x & 0xFFFF0000u);
  f[2] = __uint_as_float((unsigned)v.y << 16);
  f[3] = __uint_as_float((unsigned)v.y & 0xFFFF0000u);
  f[4] = __uint_as_float((unsigned)v.z << 16);
  f[5] = __uint_as_float((unsigned)v.z & 0xFFFF0000u);
  f[6] = __uint_as_float((unsigned)v.w << 16);
  f[7] = __uint_as_float((unsigned)v.w & 0xFFFF0000u);
}

// ---------------- fused: sort pass (blocks 0..GB-1) + W1 pre-pack + cursor zero (block GB) ----------------
__global__ __launch_bounds__(1024) void k_sort_wpack(const int* __restrict__ src,
                                                     const int* __restrict__ dst,
                                                     const float* __restrict__ ew,
                                                     int2* __restrict__ recsA,
                                                     int* __restrict__ gcntT,
                                                     int* __restrict__ loffB,
                                                     const float* __restrict__ W1,
                                                     unsigned short* __restrict__ wp1,
                                                     int* __restrict__ cursor,
                                                     int E, int CHUNK, int NBUK) {
  __shared__ int2 stage[SCAP];
  __shared__ int lcnt[NBUKP];
  __shared__ int loff[NBUKP];
  __shared__ int lcur[NBUKP];
  __shared__ int ssum[1024];
  const int b = blockIdx.x, t = threadIdx.x;

  if (b >= GB) {  // ---- wpack + cursor zero ----
    if (t == 0) *cursor = 0;
    for (int i = t; i < 16 * 512; i += 1024) {
      int f = i >> 9, l = (i >> 3) & 63, j = i & 7;
      int ks = f >> 2, nt = f & 3;
      int k = ks * 32 + (l >> 4) * 8 + j;
      int n = nt * 16 + (l & 15);
      wp1[i] = f2bf(W1[k * 64 + n]);
    }
    return;
  }

  // ---- sortchunk blocks ----
  const int s = b * CHUNK, e = min(E, s + CHUNK);
  const int m = e - s;

  for (int i = t; i < NBUK; i += 1024) lcnt[i] = 0;
  __syncthreads();
  for (int p = s + t; p < e; p += 1024)
    atomicAdd(&lcnt[dst[p] >> BSH], 1);
  __syncthreads();

  int c = (t < NBUK) ? lcnt[t] : 0;
  ssum[t] = c;
  __syncthreads();
  for (int off = 1; off < 1024; off <<= 1) {
    int v = (t >= off) ? ssum[t - off] : 0;
    __syncthreads();
    ssum[t] += v;
    __syncthreads();
  }
  if (t < NBUK) { loff[t] = ssum[t] - c; lcur[t] = ssum[t] - c; }
  if (t == 0) loff[NBUK] = m;
  __syncthreads();

  for (int p = s + t; p < e; p += 1024) {
    int d = dst[p];
    int bk = d >> BSH;
    int pos = atomicAdd(&lcur[bk], 1);
    stage[pos] = make_int2(src[p] | ((d & (BNODES - 1)) << 17), __float_as_int(ew[p]));
  }
  __syncthreads();

  for (int p = t; p < m; p += 1024) recsA[s + p] = stage[p];
  for (int i = t; i < NBUK; i += 1024) gcntT[i * GB + b] = lcnt[i];
  for (int i = t; i <= NBUK; i += 1024) loffB[b * NBUKP + i] = loff[i];
}

// ---------------- per-bucket finalize: local scan + atomic cursor, no global scan ----------------
__global__ __launch_bounds__(256) void k_bucket(const int2* __restrict__ recsA,
                                                const int* __restrict__ gcntT,
                                                const int* __restrict__ loffB,
                                                int2* __restrict__ pairs,
                                                float* __restrict__ dinv,
                                                int* __restrict__ rowstart,
                                                int* __restrict__ rowend,
                                                int* __restrict__ cursor,
                                                int N, int E, int CHUNK, int NBUK) {
  __shared__ int2 lrec[BCAP];
  __shared__ int2 sout[BCAP];
  __shared__ int boff[256];
  __shared__ int cnt[BNODES];
  __shared__ int cur[BNODES];
  __shared__ int sbuf[BNODES];
  __shared__ float degs[BNODES];
  __shared__ float dl[BNODES];
  __shared__ int basesh;
  const int b = blockIdx.x;
  const int t = threadIdx.x;

  // scan this bucket's 256 per-source-block counts
  int bc = gcntT[b * GB + t];
  boff[t] = bc;
  __syncthreads();
  for (int off = 1; off < 256; off <<= 1) {
    int v = (t >= off) ? boff[t - off] : 0;
    __syncthreads();
    boff[t] += v;
    __syncthreads();
  }
  int myoff = boff[t] - bc;       // exclusive offset for source block t
  int total = boff[255];
  if (t == 0) basesh = atomicAdd(cursor, total);
  if (t < BNODES) { cnt[t] = 0; degs[t] = 1.0f; }  // self-loop weight
  __syncthreads();
  const int bstart = basesh;
  int m = total;
  if (m > BCAP) m = BCAP;

  // gather: thread t copies source-block t's run for this bucket
  {
    int ls = loffB[t * NBUKP + b];
    int le = loffB[t * NBUKP + b + 1];
    const int2* sp = recsA + (size_t)t * CHUNK + ls;
    int len = le - ls;
    for (int j = 0; j < len; ++j) {
      if (myoff + j < BCAP) lrec[myoff + j] = sp[j];
    }
  }
  __syncthreads();

  for (int p = t; p < m; p += 256) {
    int2 r = lrec[p];
    int d = (r.x >> 17) & (BNODES - 1);
    atomicAdd(&cnt[d], 1);
    atomicAdd(&degs[d], __int_as_float(r.y));
  }
  __syncthreads();
  if (t < BNODES) sbuf[t] = cnt[t];
  __syncthreads();
  for (int off = 1; off < BNODES; off <<= 1) {
    int v = (t < BNODES && t >= off) ? sbuf[t - off] : 0;
    __syncthreads();
    if (t < BNODES) sbuf[t] += v;
    __syncthreads();
  }
  if (t < BNODES) {
    int ls = sbuf[t] - cnt[t];
    cur[t] = ls;
    float di = rsqrtf(degs[t]);
    dl[t] = di;
    int node = b * BNODES + t;
    if (node < N) {
      dinv[node] = di;
      rowstart[node] = bstart + ls;
      rowend[node] = bstart + ls + cnt[t];
    }
  }
  __syncthreads();
  for (int p = t; p < m; p += 256) {
    int2 r = lrec[p];
    int d = (r.x >> 17) & (BNODES - 1);
    int pos = atomicAdd(&cur[d], 1);
    float c = __int_as_float(r.y) * dl[d];  // ew * dinv[dst]; dinv[src] folded into xs
    sout[pos] = make_int2(r.x & 0x1FFFF, __float_as_int(c));
  }
  __syncthreads();
  for (int p = t; p < m; p += 256) pairs[bstart + p] = sout[p];
}

// ---------------- MFMA dense transform (layer 1) ----------------
template <int K, int F>
__global__ __launch_bounds__(256, 4) void mfma_gemm(const float* __restrict__ x,
                                                    const unsigned short* __restrict__ wp,
                                                    const float* __restrict__ scale,
                                                    unsigned short* __restrict__ y, int N) {
  constexpr int KS = K / 32;
  constexpr int NT = F / 16;
  const int lane = threadIdx.x & 63;
  const int quad = lane >> 4;
  const int col = lane & 15;
  const int row0 = blockIdx.x * 64 + (threadIdx.x >> 6) * 16;
  if (row0 >= N) return;

  bfrag bf[KS * NT];
#pragma unroll
  for (int f = 0; f < KS * NT; ++f)
    bf[f] = *(const bfrag*)(wp + f * 512 + lane * 8);

  cfrag acc[NT] = {};

  int row_a = row0 + col;
  if (row_a >= N) row_a = N - 1;
  const float* xp = x + (size_t)row_a * K + quad * 8;

#pragma unroll
  for (int ks = 0; ks < KS; ++ks) {
    float4 a0 = *(const float4*)(xp + ks * 32);
    float4 a1 = *(const float4*)(xp + ks * 32 + 4);
    bfrag af;
    af[0] = (short)f2bf(a0.x); af[1] = (short)f2bf(a0.y);
    af[2] = (short)f2bf(a0.z); af[3] = (short)f2bf(a0.w);
    af[4] = (short)f2bf(a1.x); af[5] = (short)f2bf(a1.y);
    af[6] = (short)f2bf(a1.z); af[7] = (short)f2bf(a1.w);
#pragma unroll
    for (int nt = 0; nt < NT; ++nt)
      acc[nt] = __builtin_amdgcn_mfma_f32_16x16x32_bf16(af, bf[ks * NT + nt], acc[nt], 0, 0, 0);
  }

  float scr[4];
#pragma unroll
  for (int r = 0; r < 4; ++r) {
    int row = row0 + quad * 4 + r;
    scr[r] = (row < N) ? scale[row] : 0.f;
  }
#pragma unroll
  for (int nt = 0; nt < NT; ++nt)
#pragma unroll
    for (int r = 0; r < 4; ++r) {
      int row = row0 + quad * 4 + r;
      if (row < N)
        y[(size_t)row * F + nt * 16 + col] = f2bf(scr[r] * acc[nt][r]);
    }
}

// ---------------- fused pull(64) + gemm2: xs2 = bf16(dinv * (relu(pull(xs1)) @ W2)) ----------------
// 256 threads = 32 nodes x 8 lanes. Phase A: edge aggregation into acc; relu -> LDS rows.
// Phase B: 64->32 matvec per node with W2 in LDS (fp32), scaled by dinv, bf16 store.
__global__ __launch_bounds__(256) void pull_fuse(const unsigned short* __restrict__ xs,
                                                 const int2* __restrict__ pairs,
                                                 const int* __restrict__ rowstart,
                                                 const int* __restrict__ rowend,
                                                 const float* __restrict__ dinv,
                                                 const float* __restrict__ b,
                                                 const float* __restrict__ W2,
                                                 unsigned short* __restrict__ xs2,
                                                 int N, int E) {
  __shared__ float rows[32 * 64];   // 8 KB
  __shared__ float w2s[64 * 32];    // 8 KB
  const int t = threadIdx.x;
  for (int i = t; i < 64 * 32; i += 256) w2s[i] = W2[i];

  const int g = blockIdx.x * 32 + t / 8;
  const int n = t / 8;
  const int f8 = (t % 8) * 8;

  if (g < N) {
    const int start = rowstart[g];
    const int end = rowend[g];
    const float di = dinv[g];

    float acc[8];
    {
      int4 v = *(const int4*)&xs[(size_t)g * HID + f8];
      float xf[8];
      bf8_to_f32(v, xf);
      float4 b0 = *(const float4*)&b[f8];
      float4 b1 = *(const float4*)&b[f8 + 4];
      acc[0] = fmaf(di, xf[0], b0.x); acc[1] = fmaf(di, xf[1], b0.y);
      acc[2] = fmaf(di, xf[2], b0.z); acc[3] = fmaf(di, xf[3], b0.w);
      acc[4] = fmaf(di, xf[4], b1.x); acc[5] = fmaf(di, xf[5], b1.y);
      acc[6] = fmaf(di, xf[6], b1.z); acc[7] = fmaf(di, xf[7], b1.w);
    }

    int p = start;
    for (; p + 2 <= end; p += 2) {
      int2 p0 = pairs[p];
      int2 p1 = pairs[p + 1];
      int4 v0 = *(const int4*)&xs[(size_t)p0.x * HID + f8];
      int4 v1 = *(const int4*)&xs[(size_t)p1.x * HID + f8];
      float c0 = __int_as_float(p0.y), c1 = __int_as_float(p1.y);
      float x0[8], x1[8];
      bf8_to_f32(v0, x0);
      bf8_to_f32(v1, x1);
#pragma unroll
      for (int j = 0; j < 8; ++j) acc[j] = fmaf(c0, x0[j], acc[j]);
#pragma unroll
      for (int j = 0; j < 8; ++j) acc[j] = fmaf(c1, x1[j], acc[j]);
    }
    if (p < end) {
      int2 pa = pairs[p];
      int4 va = *(const int4*)&xs[(size_t)pa.x * HID + f8];
      float ca = __int_as_float(pa.y);
      float xa[8];
      bf8_to_f32(va, xa);
#pragma unroll
      for (int j = 0; j < 8; ++j) acc[j] = fmaf(ca, xa[j], acc[j]);
    }
#pragma unroll
    for (int j = 0; j < 8; ++j) rows[n * 64 + f8 + j] = fmaxf(acc[j], 0.f);
  }
  __syncthreads();

  // Phase B: thread t -> node n = t/8, outputs o0..o0+3 where o0 = (t%8)*4
  const int o0 = (t % 8) * 4;
  if (g < N) {
    float4 o = make_float4(0.f, 0.f, 0.f, 0.f);
    const float* rp = &rows[n * 64];
#pragma unroll 8
    for (int k = 0; k < 64; ++k) {
      float r = rp[k];
      float4 wv = *(const float4*)&w2s[k * 32 + o0];
      o.x = fmaf(r, wv.x, o.x); o.y = fmaf(r, wv.y, o.y);
      o.z = fmaf(r, wv.z, o.z); o.w = fmaf(r, wv.w, o.w);
    }
    float di = dinv[g];
    ushort4 ov;
    ov.x = f2bf(di * o.x); ov.y = f2bf(di * o.y);
    ov.z = f2bf(di * o.z); ov.w = f2bf(di * o.w);
    *(ushort4*)&xs2[(size_t)g * CLS + o0] = ov;
  }
}

// ---------------- final pull (layer 2): fp32 out ----------------
__global__ __launch_bounds__(256) void pull_out(const unsigned short* __restrict__ xs,
                                                const int2* __restrict__ pairs,
                                                const int* __restrict__ rowstart,
                                                const int* __restrict__ rowend,
                                                const float* __restrict__ dinv,
                                                const float* __restrict__ b,
                                                float* __restrict__ out, int N, int E) {
  constexpr int LPN = CLS / 8;      // 4 lanes per node
  constexpr int NPB = 256 / LPN;    // 64 nodes per block
  const int g = blockIdx.x * NPB + threadIdx.x / LPN;
  const int f8 = (threadIdx.x % LPN) * 8;
  if (g >= N) return;

  const int start = rowstart[g];
  const int end = rowend[g];
  const float di = dinv[g];

  float acc[8];
  {
    int4 v = *(const int4*)&xs[(size_t)g * CLS + f8];
    float xf[8];
    bf8_to_f32(v, xf);
    float4 b0 = *(const float4*)&b[f8];
    float4 b1 = *(const float4*)&b[f8 + 4];
    acc[0] = fmaf(di, xf[0], b0.x); acc[1] = fmaf(di, xf[1], b0.y);
    acc[2] = fmaf(di, xf[2], b0.z); acc[3] = fmaf(di, xf[3], b0.w);
    acc[4] = fmaf(di, xf[4], b1.x); acc[5] = fmaf(di, xf[5], b1.y);
    acc[6] = fmaf(di, xf[6], b1.z); acc[7] = fmaf(di, xf[7], b1.w);
  }

  int p = start;
  for (; p + 2 <= end; p += 2) {
    int2 p0 = pairs[p];
    int2 p1 = pairs[p + 1];
    int4 v0 = *(const int4*)&xs[(size_t)p0.x * CLS + f8];
    int4 v1 = *(const int4*)&xs[(size_t)p1.x * CLS + f8];
    float c0 = __int_as_float(p0.y), c1 = __int_as_float(p1.y);
    float x0[8], x1[8];
    bf8_to_f32(v0, x0);
    bf8_to_f32(v1, x1);
#pragma unroll
    for (int j = 0; j < 8; ++j) acc[j] = fmaf(c0, x0[j], acc[j]);
#pragma unroll
    for (int j = 0; j < 8; ++j) acc[j] = fmaf(c1, x1[j], acc[j]);
  }
  if (p < end) {
    int2 pa = pairs[p];
    int4 va = *(const int4*)&xs[(size_t)pa.x * CLS + f8];
    float ca = __int_as_float(pa.y);
    float xa[8];
    bf8_to_f32(va, xa);
#pragma unroll
    for (int j = 0; j < 8; ++j) acc[j] = fmaf(ca, xa[j], acc[j]);
  }
  *(float4*)&out[(size_t)g * CLS + f8] = make_float4(acc[0], acc[1], acc[2], acc[3]);
  *(float4*)&out[(size_t)g * CLS + f8 + 4] = make_float4(acc[4], acc[5], acc[6], acc[7]);
}

// ---------------- launch ----------------
extern "C" void kernel_launch(void* const* d_in, const int* in_sizes, int n_in,
                              void* d_out, int out_size, void* d_ws, size_t ws_size,
                              hipStream_t stream) {
  const float* x  = (const float*)d_in[0];
  const int*   ei = (const int*)d_in[1];
  const float* ew = (const float*)d_in[2];
  const float* W1 = (const float*)d_in[3];
  const float* b1 = (const float*)d_in[4];
  const float* W2 = (const float*)d_in[5];
  const float* b2 = (const float*)d_in[6];
  float* out = (float*)d_out;

  const int N = in_sizes[0] / FIN;
  const int E = in_sizes[2];
  const int* src = ei;        // edge_index[0]
  const int* dst = ei + E;    // edge_index[1]

  const int NBUK = (N + BNODES - 1) >> BSH;   // 782 for N=100000
  const int M = NBUK * GB;                    // (bucket, block) count table
  const int CHUNK = (E + GB - 1) / GB;        // 6250 (<= SCAP)

  // workspace layout (16B-aligned by construction)
  float* wsf      = (float*)d_ws;
  float* dinv     = wsf;                       // N f32
  int*   rowstart = (int*)(dinv + N);          // N i32
  int*   rowend   = rowstart + N;              // N i32
  int*   gcntT    = rowend + N;                // M i32
  int*   loffB    = gcntT + M;                 // GB*NBUKP i32
  int*   cursor   = loffB + GB * NBUKP;        // 1 i32 (+3 pad)
  int2*  recsA    = (int2*)(cursor + 4);       // E int2 (block-sorted chunks)
  int2*  pairs    = recsA + E;                 // E int2 (bucket-grouped final)
  unsigned short* xs1 = (unsigned short*)(pairs + E);    // N*HID bf16
  unsigned short* xs2 = xs1 + (size_t)N * HID;           // N*CLS bf16
  unsigned short* wp1 = xs2 + (size_t)N * CLS;           // 8192 bf16

  k_sort_wpack<<<GB + 1, 1024, 0, stream>>>(src, dst, ew, recsA, gcntT, loffB,
                                            W1, wp1, cursor, E, CHUNK, NBUK);
  k_bucket<<<NBUK, 256, 0, stream>>>(recsA, gcntT, loffB, pairs, dinv, rowstart,
                                     rowend, cursor, N, E, CHUNK, NBUK);

  // layer 1: xs1 = bf16(dinv * (x @ W1))
  mfma_gemm<FIN, HID><<<(N + 63) / 64, 256, 0, stream>>>(x, wp1, dinv, xs1, N);
  // fused: out1 = relu(pull(xs1)); xs2 = bf16(dinv * (out1 @ W2))
  pull_fuse<<<(N + 31) / 32, 256, 0, stream>>>(xs1, pairs, rowstart, rowend, dinv,
                                               b1, W2, xs2, N, E);
  // layer 2 final: out = pull(xs2) (fp32)
  pull_out<<<(N + 63) / 64, 256, 0, stream>>>(xs2, pairs, rowstart, rowend, dinv,
                                              b2, out, N, E);
}

// Round 16
// 269.177 us; speedup vs baseline: 1.0018x; 1.0018x over previous
//
#include <hip/hip_runtime.h>

#define FIN 128
#define HID 64
#define CLS 32

#define BSH 7            // bucket covers 128 nodes
#define BNODES 128
#define GB 256           // chunks / blocks in sort pass (CHUNK=6250 @ E=1.6M)
#define BCAP 4096        // max records per bucket staged in LDS (mean ~2046)
#define SCAP 6272        // >= CHUNK: per-block staging capacity
#define NBUKP 800        // padded per-block loffB stride (>= NBUK+1)

using bfrag = __attribute__((ext_vector_type(8))) short;   // 8 bf16 (4 VGPRs)
using cfrag = __attribute__((ext_vector_type(4))) float;   // 4 fp32 acc

__device__ inline unsigned short f2bf(float x) {
  unsigned u = __float_as_uint(x);
  return (unsigned short)((u + 0x7FFFu + ((u >> 16) & 1u)) >> 16);
}
__device__ inline void bf8_to_f32(int4 v, float* f) {
  f[0] = __uint_as_float((unsigned)v.x << 16);
  f[1] = __uint_as_float((unsigned)v.x & 0xFFFF0000u);
  f[2] = __uint_as_float((unsigned)v.y << 16);
  f[3] = __uint_as_float((unsigned)v.y & 0xFFFF0000u);
  f[4] = __uint_as_float((unsigned)v.z << 16);
  f[5] = __uint_as_float((unsigned)v.z & 0xFFFF0000u);
  f[6] = __uint_as_float((unsigned)v.w << 16);
  f[7] = __uint_as_float((unsigned)v.w & 0xFFFF0000u);
}

// ---------------- fused: sort pass (blocks 0..GB-1) + W1/W2 pre-pack + cursor zero (block GB) ----------------
__global__ __launch_bounds__(1024) void k_sort_wpack(const int* __restrict__ src,
                                                     const int* __restrict__ dst,
                                                     const float* __restrict__ ew,
                                                     int2* __restrict__ recsA,
                                                     int* __restrict__ gcntT,
                                                     int* __restrict__ loffB,
                                                     const float* __restrict__ W1,
                                                     const float* __restrict__ W2,
                                                     unsigned short* __restrict__ wp1,
                                                     unsigned short* __restrict__ wp2,
                                                     int* __restrict__ cursor,
                                                     int E, int CHUNK, int NBUK) {
  __shared__ int2 stage[SCAP];
  __shared__ int lcnt[NBUKP];
  __shared__ int loff[NBUKP];
  __shared__ int lcur[NBUKP];
  __shared__ int ssum[1024];
  const int b = blockIdx.x, t = threadIdx.x;

  if (b >= GB) {  // ---- wpack + cursor zero ----
    if (t == 0) *cursor = 0;
    for (int i = t; i < 16 * 512; i += 1024) {
      int f = i >> 9, l = (i >> 3) & 63, j = i & 7;
      int ks = f >> 2, nt = f & 3;
      int k = ks * 32 + (l >> 4) * 8 + j;
      int n = nt * 16 + (l & 15);
      wp1[i] = f2bf(W1[k * 64 + n]);
    }
    for (int i = t; i < 4 * 512; i += 1024) {
      int f = i >> 9, l = (i >> 3) & 63, j = i & 7;
      int ks = f >> 1, nt = f & 1;
      int k = ks * 32 + (l >> 4) * 8 + j;
      int n = nt * 16 + (l & 15);
      wp2[i] = f2bf(W2[k * 32 + n]);
    }
    return;
  }

  // ---- sortchunk blocks ----
  const int s = b * CHUNK, e = min(E, s + CHUNK);
  const int m = e - s;

  for (int i = t; i < NBUK; i += 1024) lcnt[i] = 0;
  __syncthreads();
  for (int p = s + t; p < e; p += 1024)
    atomicAdd(&lcnt[dst[p] >> BSH], 1);
  __syncthreads();

  int c = (t < NBUK) ? lcnt[t] : 0;
  ssum[t] = c;
  __syncthreads();
  for (int off = 1; off < 1024; off <<= 1) {
    int v = (t >= off) ? ssum[t - off] : 0;
    __syncthreads();
    ssum[t] += v;
    __syncthreads();
  }
  if (t < NBUK) { loff[t] = ssum[t] - c; lcur[t] = ssum[t] - c; }
  if (t == 0) loff[NBUK] = m;
  __syncthreads();

  for (int p = s + t; p < e; p += 1024) {
    int d = dst[p];
    int bk = d >> BSH;
    int pos = atomicAdd(&lcur[bk], 1);
    stage[pos] = make_int2(src[p] | ((d & (BNODES - 1)) << 17), __float_as_int(ew[p]));
  }
  __syncthreads();

  for (int p = t; p < m; p += 1024) recsA[s + p] = stage[p];
  for (int i = t; i < NBUK; i += 1024) gcntT[i * GB + b] = lcnt[i];
  for (int i = t; i <= NBUK; i += 1024) loffB[b * NBUKP + i] = loff[i];
}

// ---------------- per-bucket finalize: local scan + atomic cursor, no global scan ----------------
__global__ __launch_bounds__(256) void k_bucket(const int2* __restrict__ recsA,
                                                const int* __restrict__ gcntT,
                                                const int* __restrict__ loffB,
                                                int2* __restrict__ pairs,
                                                float* __restrict__ dinv,
                                                int* __restrict__ rowstart,
                                                int* __restrict__ rowend,
                                                int* __restrict__ cursor,
                                                int N, int E, int CHUNK, int NBUK) {
  __shared__ int2 lrec[BCAP];
  __shared__ int2 sout[BCAP];
  __shared__ int boff[256];
  __shared__ int cnt[BNODES];
  __shared__ int cur[BNODES];
  __shared__ int sbuf[BNODES];
  __shared__ float degs[BNODES];
  __shared__ float dl[BNODES];
  __shared__ int basesh;
  const int b = blockIdx.x;
  const int t = threadIdx.x;

  // scan this bucket's 256 per-source-block counts
  int bc = gcntT[b * GB + t];
  boff[t] = bc;
  __syncthreads();
  for (int off = 1; off < 256; off <<= 1) {
    int v = (t >= off) ? boff[t - off] : 0;
    __syncthreads();
    boff[t] += v;
    __syncthreads();
  }
  int myoff = boff[t] - bc;       // exclusive offset for source block t
  int total = boff[255];
  if (t == 0) basesh = atomicAdd(cursor, total);
  if (t < BNODES) { cnt[t] = 0; degs[t] = 1.0f; }  // self-loop weight
  __syncthreads();
  const int bstart = basesh;
  int m = total;
  if (m > BCAP) m = BCAP;

  // gather: thread t copies source-block t's run for this bucket
  {
    int ls = loffB[t * NBUKP + b];
    int le = loffB[t * NBUKP + b + 1];
    const int2* sp = recsA + (size_t)t * CHUNK + ls;
    int len = le - ls;
    for (int j = 0; j < len; ++j) {
      if (myoff + j < BCAP) lrec[myoff + j] = sp[j];
    }
  }
  __syncthreads();

  for (int p = t; p < m; p += 256) {
    int2 r = lrec[p];
    int d = (r.x >> 17) & (BNODES - 1);
    atomicAdd(&cnt[d], 1);
    atomicAdd(&degs[d], __int_as_float(r.y));
  }
  __syncthreads();
  if (t < BNODES) sbuf[t] = cnt[t];
  __syncthreads();
  for (int off = 1; off < BNODES; off <<= 1) {
    int v = (t < BNODES && t >= off) ? sbuf[t - off] : 0;
    __syncthreads();
    if (t < BNODES) sbuf[t] += v;
    __syncthreads();
  }
  if (t < BNODES) {
    int ls = sbuf[t] - cnt[t];
    cur[t] = ls;
    float di = rsqrtf(degs[t]);
    dl[t] = di;
    int node = b * BNODES + t;
    if (node < N) {
      dinv[node] = di;
      rowstart[node] = bstart + ls;
      rowend[node] = bstart + ls + cnt[t];
    }
  }
  __syncthreads();
  for (int p = t; p < m; p += 256) {
    int2 r = lrec[p];
    int d = (r.x >> 17) & (BNODES - 1);
    int pos = atomicAdd(&cur[d], 1);
    float c = __int_as_float(r.y) * dl[d];  // ew * dinv[dst]; dinv[src] folded into xs
    sout[pos] = make_int2(r.x & 0x1FFFF, __float_as_int(c));
  }
  __syncthreads();
  for (int p = t; p < m; p += 256) pairs[bstart + p] = sout[p];
}

// ---------------- MFMA dense transform ----------------
// y_bf16 = scale[row] * (x @ W); A from fp32 (ABF16=false) or bf16 (ABF16=true, relu pre-applied)
template <int K, int F, bool ABF16>
__global__ __launch_bounds__(256, 4) void mfma_gemm(const void* __restrict__ xv,
                                                    const unsigned short* __restrict__ wp,
                                                    const float* __restrict__ scale,
                                                    unsigned short* __restrict__ y, int N) {
  constexpr int KS = K / 32;
  constexpr int NT = F / 16;
  const int lane = threadIdx.x & 63;
  const int quad = lane >> 4;
  const int col = lane & 15;
  const int row0 = blockIdx.x * 64 + (threadIdx.x >> 6) * 16;
  if (row0 >= N) return;

  bfrag bf[KS * NT];
#pragma unroll
  for (int f = 0; f < KS * NT; ++f)
    bf[f] = *(const bfrag*)(wp + f * 512 + lane * 8);

  cfrag acc[NT] = {};

  int row_a = row0 + col;
  if (row_a >= N) row_a = N - 1;

#pragma unroll
  for (int ks = 0; ks < KS; ++ks) {
    bfrag af;
    if (ABF16) {
      const unsigned short* xp = (const unsigned short*)xv + (size_t)row_a * K + quad * 8;
      af = *(const bfrag*)(xp + ks * 32);
    } else {
      const float* xp = (const float*)xv + (size_t)row_a * K + quad * 8;
      float4 a0 = *(const float4*)(xp + ks * 32);
      float4 a1 = *(const float4*)(xp + ks * 32 + 4);
      af[0] = (short)f2bf(a0.x); af[1] = (short)f2bf(a0.y);
      af[2] = (short)f2bf(a0.z); af[3] = (short)f2bf(a0.w);
      af[4] = (short)f2bf(a1.x); af[5] = (short)f2bf(a1.y);
      af[6] = (short)f2bf(a1.z); af[7] = (short)f2bf(a1.w);
    }
#pragma unroll
    for (int nt = 0; nt < NT; ++nt)
      acc[nt] = __builtin_amdgcn_mfma_f32_16x16x32_bf16(af, bf[ks * NT + nt], acc[nt], 0, 0, 0);
  }

  float scr[4];
#pragma unroll
  for (int r = 0; r < 4; ++r) {
    int row = row0 + quad * 4 + r;
    scr[r] = (row < N) ? scale[row] : 0.f;
  }
#pragma unroll
  for (int nt = 0; nt < NT; ++nt)
#pragma unroll
    for (int r = 0; r < 4; ++r) {
      int row = row0 + quad * 4 + r;
      if (row < N)
        y[(size_t)row * F + nt * 16 + col] = f2bf(scr[r] * acc[nt][r]);
    }
}

// ---------------- pull aggregation: direct pair loads, bf16 gather, no LDS ----------------
// out = b + dinv[d]*xs[d] + sum coef*xs[src].  BF16OUT: store bf16(relu(out)).
template <int F, bool BF16OUT>
__global__ __launch_bounds__(256) void pull_agg(const unsigned short* __restrict__ xs,
                                                const int2* __restrict__ pairs,
                                                const int* __restrict__ rowstart,
                                                const int* __restrict__ rowend,
                                                const float* __restrict__ dinv,
                                                const float* __restrict__ b,
                                                void* __restrict__ outv, int N) {
  constexpr int LPN = F / 8;        // lanes per node (8 features each, 16B loads)
  constexpr int NPB = 256 / LPN;
  const int g = blockIdx.x * NPB + threadIdx.x / LPN;
  const int f8 = (threadIdx.x % LPN) * 8;
  if (g >= N) return;

  const int start = rowstart[g];
  const int end = rowend[g];
  const float di = dinv[g];

  float acc[8];
  {
    int4 v = *(const int4*)&xs[(size_t)g * F + f8];
    float xf[8];
    bf8_to_f32(v, xf);
    float4 b0 = *(const float4*)&b[f8];
    float4 b1 = *(const float4*)&b[f8 + 4];
    acc[0] = fmaf(di, xf[0], b0.x); acc[1] = fmaf(di, xf[1], b0.y);
    acc[2] = fmaf(di, xf[2], b0.z); acc[3] = fmaf(di, xf[3], b0.w);
    acc[4] = fmaf(di, xf[4], b1.x); acc[5] = fmaf(di, xf[5], b1.y);
    acc[6] = fmaf(di, xf[6], b1.z); acc[7] = fmaf(di, xf[7], b1.w);
  }

  int p = start;
  for (; p + 2 <= end; p += 2) {
    int2 p0 = pairs[p];
    int2 p1 = pairs[p + 1];
    int4 v0 = *(const int4*)&xs[(size_t)p0.x * F + f8];
    int4 v1 = *(const int4*)&xs[(size_t)p1.x * F + f8];
    float c0 = __int_as_float(p0.y), c1 = __int_as_float(p1.y);
    float x0[8], x1[8];
    bf8_to_f32(v0, x0);
    bf8_to_f32(v1, x1);
#pragma unroll
    for (int j = 0; j < 8; ++j) acc[j] = fmaf(c0, x0[j], acc[j]);
#pragma unroll
    for (int j = 0; j < 8; ++j) acc[j] = fmaf(c1, x1[j], acc[j]);
  }
  if (p < end) {
    int2 pa = pairs[p];
    int4 va = *(const int4*)&xs[(size_t)pa.x * F + f8];
    float ca = __int_as_float(pa.y);
    float xa[8];
    bf8_to_f32(va, xa);
#pragma unroll
    for (int j = 0; j < 8; ++j) acc[j] = fmaf(ca, xa[j], acc[j]);
  }

  if (BF16OUT) {
    unsigned short* out = (unsigned short*)outv;
    ushort4 o0, o1;
    o0.x = f2bf(fmaxf(acc[0], 0.f)); o0.y = f2bf(fmaxf(acc[1], 0.f));
    o0.z = f2bf(fmaxf(acc[2], 0.f)); o0.w = f2bf(fmaxf(acc[3], 0.f));
    o1.x = f2bf(fmaxf(acc[4], 0.f)); o1.y = f2bf(fmaxf(acc[5], 0.f));
    o1.z = f2bf(fmaxf(acc[6], 0.f)); o1.w = f2bf(fmaxf(acc[7], 0.f));
    *(ushort4*)&out[(size_t)g * F + f8] = o0;
    *(ushort4*)&out[(size_t)g * F + f8 + 4] = o1;
  } else {
    float* out = (float*)outv;
    *(float4*)&out[(size_t)g * F + f8] = make_float4(acc[0], acc[1], acc[2], acc[3]);
    *(float4*)&out[(size_t)g * F + f8 + 4] = make_float4(acc[4], acc[5], acc[6], acc[7]);
  }
}

// ---------------- launch ----------------
extern "C" void kernel_launch(void* const* d_in, const int* in_sizes, int n_in,
                              void* d_out, int out_size, void* d_ws, size_t ws_size,
                              hipStream_t stream) {
  const float* x  = (const float*)d_in[0];
  const int*   ei = (const int*)d_in[1];
  const float* ew = (const float*)d_in[2];
  const float* W1 = (const float*)d_in[3];
  const float* b1 = (const float*)d_in[4];
  const float* W2 = (const float*)d_in[5];
  const float* b2 = (const float*)d_in[6];
  float* out = (float*)d_out;

  const int N = in_sizes[0] / FIN;
  const int E = in_sizes[2];
  const int* src = ei;        // edge_index[0]
  const int* dst = ei + E;    // edge_index[1]

  const int NBUK = (N + BNODES - 1) >> BSH;   // 782 for N=100000
  const int M = NBUK * GB;                    // (bucket, block) count table
  const int CHUNK = (E + GB - 1) / GB;        // 6250 (<= SCAP)

  // workspace layout (16B-aligned by construction)
  float* wsf      = (float*)d_ws;
  float* dinv     = wsf;                       // N f32
  int*   rowstart = (int*)(dinv + N);          // N i32
  int*   rowend   = rowstart + N;              // N i32
  int*   gcntT    = rowend + N;                // M i32
  int*   loffB    = gcntT + M;                 // GB*NBUKP i32
  int*   cursor   = loffB + GB * NBUKP;        // 1 i32 (+3 pad)
  int2*  recsA    = (int2*)(cursor + 4);       // E int2 (block-sorted chunks)
  int2*  pairs    = recsA + E;                 // E int2 (bucket-grouped final)
  unsigned short* xs1 = (unsigned short*)(pairs + E);    // N*HID bf16
  unsigned short* out1b = xs1 + (size_t)N * HID;         // N*HID bf16 (relu'd)
  unsigned short* xs2 = xs1;                   // alias: xs1 dead after pull_agg<HID>
  unsigned short* wp1 = out1b + (size_t)N * HID;         // 8192 bf16
  unsigned short* wp2 = wp1 + 16 * 512;                  // 2048 bf16

  k_sort_wpack<<<GB + 1, 1024, 0, stream>>>(src, dst, ew, recsA, gcntT, loffB,
                                            W1, W2, wp1, wp2, cursor, E, CHUNK, NBUK);
  k_bucket<<<NBUK, 256, 0, stream>>>(recsA, gcntT, loffB, pairs, dinv, rowstart,
                                     rowend, cursor, N, E, CHUNK, NBUK);

  // layer 1: xs1 = bf16(dinv * (x @ W1));  out1b = bf16(relu(pull(xs1)))
  mfma_gemm<FIN, HID, false><<<(N + 63) / 64, 256, 0, stream>>>(x, wp1, dinv, xs1, N);
  pull_agg<HID, true><<<(N + 31) / 32, 256, 0, stream>>>(xs1, pairs, rowstart, rowend,
                                                         dinv, b1, out1b, N);

  // layer 2: xs2 = bf16(dinv * (out1b @ W2));  out = pull(xs2)  (fp32)
  mfma_gemm<HID, CLS, true><<<(N + 63) / 64, 256, 0, stream>>>(out1b, wp2, dinv, xs2, N);
  pull_agg<CLS, false><<<(N + 63) / 64, 256, 0, stream>>>(xs2, pairs, rowstart, rowend,
                                                          dinv, b2, out, N);
}

// Round 17
// 239.901 us; speedup vs baseline: 1.1241x; 1.1220x over previous
//
#include <hip/hip_runtime.h>

#define FIN 128
#define HID 64
#define CLS 32

#define BSH 7            // bucket covers 128 nodes
#define BNODES 128
#define GB 256           // chunks / blocks in sort pass (CHUNK=6250 @ E=1.6M)
#define BCAP 4096        // max records per bucket staged in LDS (mean ~2046)
#define SCAP 6272        // >= CHUNK: per-block staging capacity
#define NBUKP 800        // padded per-block loffB stride (>= NBUK+1)

// dynamic-LDS layout for the fused first kernel
#define SM_STAGE 0                     // int2[SCAP]   = 50176 B
#define SM_LCNT  50176                 // int[NBUKP]*3 = 9600 B
#define SM_SSUM  (50176 + 9600)       // int[1024]    = 4096 B
#define SM_BYTES (50176 + 9600 + 4096) // 63872 (gemm path reuses first 32 KB)

using bfrag = __attribute__((ext_vector_type(8))) short;   // 8 bf16 (4 VGPRs)
using cfrag = __attribute__((ext_vector_type(4))) float;   // 4 fp32 acc

__device__ inline unsigned short f2bf(float x) {
  unsigned u = __float_as_uint(x);
  return (unsigned short)((u + 0x7FFFu + ((u >> 16) & 1u)) >> 16);
}
__device__ inline void bf8_to_f32(int4 v, float* f) {
  f[0] = __uint_as_float((unsigned)v.x << 16);
  f[1] = __uint_as_float((unsigned)v.x & 0xFFFF0000u);
  f[2] = __uint_as_float((unsigned)v.y << 16);
  f[3] = __uint_as_float((unsigned)v.y & 0xFFFF0000u);
  f[4] = __uint_as_float((unsigned)v.z << 16);
  f[5] = __uint_as_float((unsigned)v.z & 0xFFFF0000u);
  f[6] = __uint_as_float((unsigned)v.w << 16);
  f[7] = __uint_as_float((unsigned)v.w & 0xFFFF0000u);
}

// ---------------- fused first dispatch ----------------
// blocks [0,GB):       block-local counting sort of edge chunks (R14-proven)
// block GB:            W2 pre-pack (B-frag order)
// blocks (GB, GB+NG]:  gemm1: xs1 = bf16(x @ W1)  (UNSCALED — dinv deferred to pull)
__global__ __launch_bounds__(1024) void k_sort_gemm(const int* __restrict__ src,
                                                    const int* __restrict__ dst,
                                                    const float* __restrict__ ew,
                                                    int2* __restrict__ recsA,
                                                    int* __restrict__ gcntT,
                                                    int* __restrict__ loffB,
                                                    const float* __restrict__ W1,
                                                    const float* __restrict__ W2,
                                                    unsigned short* __restrict__ wp2,
                                                    const float* __restrict__ x,
                                                    unsigned short* __restrict__ xs1,
                                                    int E, int CHUNK, int NBUK, int N) {
  extern __shared__ char sm[];
  const int b = blockIdx.x, t = threadIdx.x;

  if (b == GB) {  // ---- W2 pack ----
    for (int i = t; i < 4 * 512; i += 1024) {
      int f = i >> 9, l = (i >> 3) & 63, j = i & 7;
      int ks = f >> 1, nt = f & 1;
      int k = ks * 32 + (l >> 4) * 8 + j;
      int n = nt * 16 + (l & 15);
      wp2[i] = f2bf(W2[k * 32 + n]);
    }
    return;
  }

  if (b > GB) {  // ---- gemm1 blocks: 256 rows each (16 waves x 16-row tiles) ----
    float* w1s = (float*)sm;  // 32 KB
    for (int i = t; i < FIN * HID; i += 1024) w1s[i] = W1[i];
    __syncthreads();
    const int lane = t & 63;
    const int quad = lane >> 4;
    const int col = lane & 15;
    const int row0 = (b - GB - 1) * 256 + (t >> 6) * 16;
    if (row0 >= N) return;

    bfrag bf[16];
#pragma unroll
    for (int ks = 0; ks < 4; ++ks)
#pragma unroll
      for (int nt = 0; nt < 4; ++nt) {
        bfrag v;
#pragma unroll
        for (int j = 0; j < 8; ++j)
          v[j] = (short)f2bf(w1s[(ks * 32 + quad * 8 + j) * HID + nt * 16 + col]);
        bf[ks * 4 + nt] = v;
      }

    cfrag acc[4] = {};
    int row_a = row0 + col;
    if (row_a >= N) row_a = N - 1;
    const float* xp = x + (size_t)row_a * FIN + quad * 8;

#pragma unroll
    for (int ks = 0; ks < 4; ++ks) {
      float4 a0 = *(const float4*)(xp + ks * 32);
      float4 a1 = *(const float4*)(xp + ks * 32 + 4);
      bfrag af;
      af[0] = (short)f2bf(a0.x); af[1] = (short)f2bf(a0.y);
      af[2] = (short)f2bf(a0.z); af[3] = (short)f2bf(a0.w);
      af[4] = (short)f2bf(a1.x); af[5] = (short)f2bf(a1.y);
      af[6] = (short)f2bf(a1.z); af[7] = (short)f2bf(a1.w);
#pragma unroll
      for (int nt = 0; nt < 4; ++nt)
        acc[nt] = __builtin_amdgcn_mfma_f32_16x16x32_bf16(af, bf[ks * 4 + nt], acc[nt], 0, 0, 0);
    }
#pragma unroll
    for (int nt = 0; nt < 4; ++nt)
#pragma unroll
      for (int r = 0; r < 4; ++r) {
        int row = row0 + quad * 4 + r;
        if (row < N)
          xs1[(size_t)row * HID + nt * 16 + col] = f2bf(acc[nt][r]);
      }
    return;
  }

  // ---- sort blocks ----
  int2* stage = (int2*)(sm + SM_STAGE);
  int* lcnt = (int*)(sm + SM_LCNT);
  int* loff = lcnt + NBUKP;
  int* lcur = loff + NBUKP;
  int* ssum = (int*)(sm + SM_SSUM);

  const int s = b * CHUNK, e = min(E, s + CHUNK);
  const int m = e - s;

  for (int i = t; i < NBUK; i += 1024) lcnt[i] = 0;
  __syncthreads();
  for (int p = s + t; p < e; p += 1024)
    atomicAdd(&lcnt[dst[p] >> BSH], 1);
  __syncthreads();

  int c = (t < NBUK) ? lcnt[t] : 0;
  ssum[t] = c;
  __syncthreads();
  for (int off = 1; off < 1024; off <<= 1) {
    int v = (t >= off) ? ssum[t - off] : 0;
    __syncthreads();
    ssum[t] += v;
    __syncthreads();
  }
  if (t < NBUK) { loff[t] = ssum[t] - c; lcur[t] = ssum[t] - c; }
  if (t == 0) loff[NBUK] = m;
  __syncthreads();

  for (int p = s + t; p < e; p += 1024) {
    int d = dst[p];
    int bk = d >> BSH;
    int pos = atomicAdd(&lcur[bk], 1);
    stage[pos] = make_int2(src[p] | ((d & (BNODES - 1)) << 17), __float_as_int(ew[p]));
  }
  __syncthreads();

  for (int p = t; p < m; p += 1024) recsA[s + p] = stage[p];
  for (int i = t; i < NBUK; i += 1024) gcntT[i * GB + b] = lcnt[i];
  for (int i = t; i <= NBUK; i += 1024) loffB[b * NBUKP + i] = loff[i];
}

// ---------------- 2-level exclusive scan (chunk = 4096, <=256 chunks) ----------------
__global__ __launch_bounds__(256) void k_scan_sums(const int* __restrict__ counts,
                                                   int* __restrict__ bsum, int N) {
  __shared__ int s[256];
  int base = blockIdx.x * 4096 + threadIdx.x * 16;
  int t = 0;
#pragma unroll
  for (int j = 0; j < 16; ++j)
    if (base + j < N) t += counts[base + j];
  s[threadIdx.x] = t;
  __syncthreads();
  for (int off = 128; off > 0; off >>= 1) {
    if (threadIdx.x < off) s[threadIdx.x] += s[threadIdx.x + off];
    __syncthreads();
  }
  if (threadIdx.x == 0) bsum[blockIdx.x] = s[0];
}

// in-place safe; each block redundantly scans bsum[0..nb) in LDS (nb <= 256)
__global__ __launch_bounds__(256) void k_scan_emit(const int* __restrict__ counts,
                                                   const int* __restrict__ bsum,
                                                   int* __restrict__ rowstart, int N, int nb) {
  __shared__ int sb[256];
  __shared__ int s[256];
  const int t = threadIdx.x;
  int bv = (t < nb) ? bsum[t] : 0;
  sb[t] = bv;
  __syncthreads();
  for (int off = 1; off < 256; off <<= 1) {
    int u = (t >= off) ? sb[t - off] : 0;
    __syncthreads();
    sb[t] += u;
    __syncthreads();
  }
  sb[t] -= bv;  // exclusive
  __syncthreads();
  const int bbase = sb[blockIdx.x];

  int base = blockIdx.x * 4096 + t * 16;
  int c[16];
  int tsum = 0;
#pragma unroll
  for (int j = 0; j < 16; ++j) {
    c[j] = (base + j < N) ? counts[base + j] : 0;
    tsum += c[j];
  }
  s[t] = tsum;
  __syncthreads();
  for (int off = 1; off < 256; off <<= 1) {
    int v = (t >= off) ? s[t - off] : 0;
    __syncthreads();
    s[t] += v;
    __syncthreads();
  }
  int run = bbase + s[t] - tsum;  // exclusive
#pragma unroll
  for (int j = 0; j < 16; ++j) {
    if (base + j < N) rowstart[base + j] = run;
    run += c[j];
  }
}

// ---------------- per-bucket finalize (R14): node-ordered pairs via global scan ----------------
__global__ __launch_bounds__(256) void k_bucket(const int2* __restrict__ recsA,
                                                const int* __restrict__ goff,
                                                const int* __restrict__ loffB,
                                                int2* __restrict__ pairs,
                                                float* __restrict__ dinv,
                                                int* __restrict__ rowstart,
                                                int N, int E, int CHUNK, int NBUK) {
  __shared__ int2 lrec[BCAP];
  __shared__ int2 sout[BCAP];
  __shared__ int cnt[BNODES];
  __shared__ int cur[BNODES];
  __shared__ int sbuf[BNODES];
  __shared__ float degs[BNODES];
  __shared__ float dl[BNODES];
  const int b = blockIdx.x;
  const int t = threadIdx.x;
  const int bstart = goff[b * GB];
  const int bend = (b + 1 < NBUK) ? goff[(b + 1) * GB] : E;
  int m = bend - bstart;
  if (m > BCAP) m = BCAP;

  if (t < BNODES) { cnt[t] = 0; degs[t] = 1.0f; }  // self-loop weight
  __syncthreads();

  // gather: thread t copies source-block t's run for this bucket (GB == blockDim)
  {
    int ls = loffB[t * NBUKP + b];
    int le = loffB[t * NBUKP + b + 1];
    int doff = goff[b * GB + t] - bstart;
    const int2* sp = recsA + (size_t)t * CHUNK + ls;
    int len = le - ls;
    for (int j = 0; j < len; ++j) {
      if (doff + j < BCAP) lrec[doff + j] = sp[j];
    }
  }
  __syncthreads();

  for (int p = t; p < m; p += 256) {
    int2 r = lrec[p];
    int d = (r.x >> 17) & (BNODES - 1);
    atomicAdd(&cnt[d], 1);
    atomicAdd(&degs[d], __int_as_float(r.y));
  }
  __syncthreads();
  if (t < BNODES) sbuf[t] = cnt[t];
  __syncthreads();
  for (int off = 1; off < BNODES; off <<= 1) {
    int v = (t < BNODES && t >= off) ? sbuf[t - off] : 0;
    __syncthreads();
    if (t < BNODES) sbuf[t] += v;
    __syncthreads();
  }
  if (t < BNODES) {
    int ls = sbuf[t] - cnt[t];
    cur[t] = ls;
    float di = rsqrtf(degs[t]);
    dl[t] = di;
    int node = b * BNODES + t;
    if (node < N) { dinv[node] = di; rowstart[node] = bstart + ls; }
  }
  __syncthreads();
  for (int p = t; p < m; p += 256) {
    int2 r = lrec[p];
    int d = (r.x >> 17) & (BNODES - 1);
    int pos = atomicAdd(&cur[d], 1);
    float c = __int_as_float(r.y) * dl[d];  // ew * dinv[dst]
    sout[pos] = make_int2(r.x & 0x1FFFF, __float_as_int(c));
  }
  __syncthreads();
  for (int p = t; p < m; p += 256) pairs[bstart + p] = sout[p];
}

// ---------------- MFMA dense transform (layer 2): xs2 = bf16(dinv * (out1b @ W2)) ----------------
template <int K, int F>
__global__ __launch_bounds__(256, 4) void mfma_gemm2(const unsigned short* __restrict__ xv,
                                                     const unsigned short* __restrict__ wp,
                                                     const float* __restrict__ scale,
                                                     unsigned short* __restrict__ y, int N) {
  constexpr int KS = K / 32;
  constexpr int NT = F / 16;
  const int lane = threadIdx.x & 63;
  const int quad = lane >> 4;
  const int col = lane & 15;
  const int row0 = blockIdx.x * 64 + (threadIdx.x >> 6) * 16;
  if (row0 >= N) return;

  bfrag bf[KS * NT];
#pragma unroll
  for (int f = 0; f < KS * NT; ++f)
    bf[f] = *(const bfrag*)(wp + f * 512 + lane * 8);

  cfrag acc[NT] = {};
  int row_a = row0 + col;
  if (row_a >= N) row_a = N - 1;
  const unsigned short* xp = xv + (size_t)row_a * K + quad * 8;

#pragma unroll
  for (int ks = 0; ks < KS; ++ks) {
    bfrag af = *(const bfrag*)(xp + ks * 32);
#pragma unroll
    for (int nt = 0; nt < NT; ++nt)
      acc[nt] = __builtin_amdgcn_mfma_f32_16x16x32_bf16(af, bf[ks * NT + nt], acc[nt], 0, 0, 0);
  }

  float scr[4];
#pragma unroll
  for (int r = 0; r < 4; ++r) {
    int row = row0 + quad * 4 + r;
    scr[r] = (row < N) ? scale[row] : 0.f;
  }
#pragma unroll
  for (int nt = 0; nt < NT; ++nt)
#pragma unroll
    for (int r = 0; r < 4; ++r) {
      int row = row0 + quad * 4 + r;
      if (row < N)
        y[(size_t)row * F + nt * 16 + col] = f2bf(scr[r] * acc[nt][r]);
    }
}

// ---------------- pull aggregation ----------------
// DG=true  (layer 1): xs unscaled; out = b + di^2*xs[g] + sum coef*dinv[src]*xs[src]
// DG=false (layer 2): xs prescaled; out = b + di*xs[g] + sum coef*xs[src]
template <int F, bool BF16OUT, bool DG>
__global__ __launch_bounds__(256) void pull_agg(const unsigned short* __restrict__ xs,
                                                const int2* __restrict__ pairs,
                                                const int* __restrict__ rowstart,
                                                const float* __restrict__ dinv,
                                                const float* __restrict__ b,
                                                void* __restrict__ outv, int N, int E) {
  constexpr int LPN = F / 8;        // lanes per node (8 features each, 16B loads)
  constexpr int NPB = 256 / LPN;
  const int g = blockIdx.x * NPB + threadIdx.x / LPN;
  const int f8 = (threadIdx.x % LPN) * 8;
  if (g >= N) return;

  const int start = rowstart[g];
  const int end = (g + 1 < N) ? rowstart[g + 1] : E;
  const float di = dinv[g];
  const float selfc = DG ? di * di : di;

  float acc[8];
  {
    int4 v = *(const int4*)&xs[(size_t)g * F + f8];
    float xf[8];
    bf8_to_f32(v, xf);
    float4 b0 = *(const float4*)&b[f8];
    float4 b1 = *(const float4*)&b[f8 + 4];
    acc[0] = fmaf(selfc, xf[0], b0.x); acc[1] = fmaf(selfc, xf[1], b0.y);
    acc[2] = fmaf(selfc, xf[2], b0.z); acc[3] = fmaf(selfc, xf[3], b0.w);
    acc[4] = fmaf(selfc, xf[4], b1.x); acc[5] = fmaf(selfc, xf[5], b1.y);
    acc[6] = fmaf(selfc, xf[6], b1.z); acc[7] = fmaf(selfc, xf[7], b1.w);
  }

  int p = start;
  for (; p + 2 <= end; p += 2) {
    int2 p0 = pairs[p];
    int2 p1 = pairs[p + 1];
    int4 v0 = *(const int4*)&xs[(size_t)p0.x * F + f8];
    int4 v1 = *(const int4*)&xs[(size_t)p1.x * F + f8];
    float c0 = __int_as_float(p0.y), c1 = __int_as_float(p1.y);
    if (DG) { c0 *= dinv[p0.x]; c1 *= dinv[p1.x]; }
    float x0[8], x1[8];
    bf8_to_f32(v0, x0);
    bf8_to_f32(v1, x1);
#pragma unroll
    for (int j = 0; j < 8; ++j) acc[j] = fmaf(c0, x0[j], acc[j]);
#pragma unroll
    for (int j = 0; j < 8; ++j) acc[j] = fmaf(c1, x1[j], acc[j]);
  }
  if (p < end) {
    int2 pa = pairs[p];
    int4 va = *(const int4*)&xs[(size_t)pa.x * F + f8];
    float ca = __int_as_float(pa.y);
    if (DG) ca *= dinv[pa.x];
    float xa[8];
    bf8_to_f32(va, xa);
#pragma unroll
    for (int j = 0; j < 8; ++j) acc[j] = fmaf(ca, xa[j], acc[j]);
  }

  if (BF16OUT) {
    unsigned short* out = (unsigned short*)outv;
    ushort4 o0, o1;
    o0.x = f2bf(fmaxf(acc[0], 0.f)); o0.y = f2bf(fmaxf(acc[1], 0.f));
    o0.z = f2bf(fmaxf(acc[2], 0.f)); o0.w = f2bf(fmaxf(acc[3], 0.f));
    o1.x = f2bf(fmaxf(acc[4], 0.f)); o1.y = f2bf(fmaxf(acc[5], 0.f));
    o1.z = f2bf(fmaxf(acc[6], 0.f)); o1.w = f2bf(fmaxf(acc[7], 0.f));
    *(ushort4*)&out[(size_t)g * F + f8] = o0;
    *(ushort4*)&out[(size_t)g * F + f8 + 4] = o1;
  } else {
    float* out = (float*)outv;
    *(float4*)&out[(size_t)g * F + f8] = make_float4(acc[0], acc[1], acc[2], acc[3]);
    *(float4*)&out[(size_t)g * F + f8 + 4] = make_float4(acc[4], acc[5], acc[6], acc[7]);
  }
}

// ---------------- launch ----------------
extern "C" void kernel_launch(void* const* d_in, const int* in_sizes, int n_in,
                              void* d_out, int out_size, void* d_ws, size_t ws_size,
                              hipStream_t stream) {
  const float* x  = (const float*)d_in[0];
  const int*   ei = (const int*)d_in[1];
  const float* ew = (const float*)d_in[2];
  const float* W1 = (const float*)d_in[3];
  const float* b1 = (const float*)d_in[4];
  const float* W2 = (const float*)d_in[5];
  const float* b2 = (const float*)d_in[6];
  float* out = (float*)d_out;

  const int N = in_sizes[0] / FIN;
  const int E = in_sizes[2];
  const int* src = ei;        // edge_index[0]
  const int* dst = ei + E;    // edge_index[1]

  const int NBUK = (N + BNODES - 1) >> BSH;   // 782 for N=100000
  const int M = NBUK * GB;                    // (bucket, block) count table
  const int CHUNK = (E + GB - 1) / GB;        // 6250 (<= SCAP)
  const int nbM = (M + 4095) / 4096;          // scan chunks (<=256)
  const int NG = (N + 255) / 256;             // gemm1 blocks in fused launch

  // workspace layout (16B-aligned by construction)
  float* wsf      = (float*)d_ws;
  float* dinv     = wsf;                       // N f32
  int*   rowstart = (int*)(dinv + N);          // N i32
  int*   gcntT    = rowstart + N;              // M i32 (counts -> offsets in place)
  int*   loffB    = gcntT + M;                 // GB*NBUKP i32
  int*   bsum     = loffB + GB * NBUKP;        // 256 i32
  int2*  recsA    = (int2*)(bsum + 256);       // E int2 (block-sorted chunks)
  int2*  pairs    = recsA + E;                 // E int2 (node-ordered final)
  unsigned short* xs1 = (unsigned short*)(pairs + E);    // N*HID bf16 (unscaled x@W1)
  unsigned short* out1b = xs1 + (size_t)N * HID;         // N*HID bf16 (relu'd)
  unsigned short* xs2 = xs1;                   // alias: xs1 dead after pull_agg<HID>
  unsigned short* wp2 = out1b + (size_t)N * HID;         // 2048 bf16

  // fused: edge sort + W2 pack + gemm1 (xs1 = bf16(x @ W1), dinv-free)
  k_sort_gemm<<<GB + 1 + NG, 1024, SM_BYTES, stream>>>(src, dst, ew, recsA, gcntT,
                                                       loffB, W1, W2, wp2, x, xs1,
                                                       E, CHUNK, NBUK, N);
  k_scan_sums<<<nbM, 256, 0, stream>>>(gcntT, bsum, M);
  k_scan_emit<<<nbM, 256, 0, stream>>>(gcntT, bsum, gcntT, M, nbM);  // in-place
  k_bucket<<<NBUK, 256, 0, stream>>>(recsA, gcntT, loffB, pairs, dinv, rowstart,
                                     N, E, CHUNK, NBUK);

  // layer 1 aggregate: out1b = bf16(relu(b1 + di^2*xs1[g] + sum coef*dinv[s]*xs1[s]))
  pull_agg<HID, true, true><<<(N + 31) / 32, 256, 0, stream>>>(xs1, pairs, rowstart,
                                                               dinv, b1, out1b, N, E);
  // layer 2: xs2 = bf16(dinv * (out1b @ W2));  out = pull(xs2) (fp32)
  mfma_gemm2<HID, CLS><<<(N + 63) / 64, 256, 0, stream>>>(out1b, wp2, dinv, xs2, N);
  pull_agg<CLS, false, false><<<(N + 63) / 64, 256, 0, stream>>>(xs2, pairs, rowstart,
                                                                 dinv, b2, out, N, E);
}